// Round 11
// baseline (57.627 us; speedup 1.0000x reference)
//
#include <hip/hip_runtime.h>
#include <hip/hip_bf16.h>

typedef short bfrag8 __attribute__((ext_vector_type(8)));
typedef float f32x4v __attribute__((ext_vector_type(4)));
typedef unsigned short U16;
typedef unsigned int U32;

#define NN 4096
#define DD 128

static __device__ __forceinline__ U16 f2bf(float f){
  union { __hip_bfloat16 b; U16 u; } cv;
  cv.b = __float2bfloat16(f);
  return cv.u;
}

static __device__ __forceinline__ float bf2f(U32 u){
  union { float f; U32 u; } cv;
  cv.u = u << 16;
  return cv.f;
}

// A-fragment from inverted adjacency bits in low byte: bit=0 -> 1.0bf16, bit=1 -> 0
static __device__ __forceinline__ bfrag8 afragb(U32 y){
  bfrag8 a;
  #pragma unroll
  for (int e = 0; e < 8; ++e) a[e] = (y & (1u<<e)) ? (short)0 : (short)0x3F80;
  return a;
}

// ---------------- kernel 0: adj pack row-major (blocks 0..2047) + W^T (2048..2111) --
// adjb[row*128 + g] bit j = adj[row][g*32 + j] != 0. Thread reads its own 128B line.
__global__ __launch_bounds__(256) void k0_combo(const int* __restrict__ adj,
                                                U32* __restrict__ adjb,
                                                const float* __restrict__ W,
                                                U16* __restrict__ WT){
  if (blockIdx.x >= 2048){
    int i = (blockIdx.x - 2048)*256 + threadIdx.x;  // i = d*128 + dp
    int d = i >> 7, dp = i & 127;
    WT[dp*128 + d] = f2bf(W[i]);
    return;
  }
  int gid = blockIdx.x*256 + threadIdx.x;    // gid = row*128 + g
  const int4* src = reinterpret_cast<const int4*>(adj) + (size_t)gid*8;
  int4 v[8];
  #pragma unroll
  for (int c = 0; c < 8; ++c) v[c] = src[c];
  U32 m = 0;
  #pragma unroll
  for (int c = 0; c < 8; ++c){
    m |= (v[c].x != 0 ? 1u : 0u) << (c*4);
    m |= (v[c].y != 0 ? 2u : 0u) << (c*4);
    m |= (v[c].z != 0 ? 4u : 0u) << (c*4);
    m |= (v[c].w != 0 ? 8u : 0u) << (c*4);
  }
  adjb[gid] = m;
}

// ---------------- kernel 1: x2 = x*(nw+1)+nb; h = LN(x2@W) via MFMA;
// writes h_lnB (bf16 row-major) and hTt: element (b,n,d) at
// ((b*128 + n/32)*128 + d)*32 + (n&31) shorts  -> a wave's 8 B-fragment loads
// for one (tile, k-window) are 1KB fully contiguous (direct-to-register GEMM).
__global__ __launch_bounds__(256) void k1_prep(
    const float* __restrict__ x, const U16* __restrict__ WT,
    const float* __restrict__ nw, const float* __restrict__ nb,
    const float* __restrict__ gamma, const float* __restrict__ beta,
    U16* __restrict__ h_lnB, U16* __restrict__ hTt)
{
  __shared__ U16 lds[16384];                 // 32 KB: WT (swizzled), later hb[64][128]
  const int tid = threadIdx.x;
  const int lane = tid & 63, w = tid >> 6;
  const int l15 = lane & 15, grp = lane >> 4;

  // stage WT into LDS with XOR swizzle (proven R2 pattern)
  #pragma unroll
  for (int q = 0; q < 8; ++q){
    int cid = q*256 + tid;
    int dp = cid >> 4, c = cid & 15;
    *reinterpret_cast<int4*>(lds + dp*128 + ((c*8) ^ ((dp&15)<<3))) =
        *reinterpret_cast<const int4*>(WT + cid*8);
  }
  __syncthreads();

  const int rA = blockIdx.x*64 + w*16 + l15;
  const int nA = rA & 4095;
  const float wgt = nw[nA] + 1.0f, bia = nb[nA];
  const float* xr = x + (size_t)rA*DD;

  f32x4v acc[8] = {};
  #pragma unroll
  for (int ks = 0; ks < 4; ++ks){
    int d8 = ks*32 + grp*8;
    float4 xa = *reinterpret_cast<const float4*>(xr + d8);
    float4 xb = *reinterpret_cast<const float4*>(xr + d8 + 4);
    bfrag8 af;
    af[0] = (short)f2bf(xa.x*wgt + bia);
    af[1] = (short)f2bf(xa.y*wgt + bia);
    af[2] = (short)f2bf(xa.z*wgt + bia);
    af[3] = (short)f2bf(xa.w*wgt + bia);
    af[4] = (short)f2bf(xb.x*wgt + bia);
    af[5] = (short)f2bf(xb.y*wgt + bia);
    af[6] = (short)f2bf(xb.z*wgt + bia);
    af[7] = (short)f2bf(xb.w*wgt + bia);
    #pragma unroll
    for (int nf = 0; nf < 8; ++nf){
      int dp = nf*16 + l15;
      bfrag8 bf = *reinterpret_cast<const bfrag8*>(
          lds + dp*128 + ((((ks*4 + grp)*8)) ^ ((dp&15)<<3)));
      acc[nf] = __builtin_amdgcn_mfma_f32_16x16x32_bf16(af, bf, acc[nf], 0, 0, 0);
    }
  }

  float gc[8], bc[8];
  #pragma unroll
  for (int nf = 0; nf < 8; ++nf){
    int col = nf*16 + l15;
    gc[nf] = gamma[col]; bc[nf] = beta[col];
  }

  // C/D layout: col = lane&15, row = (lane>>4)*4 + r (m89-verified)
  const int rCb = blockIdx.x*64 + w*16 + grp*4;
  #pragma unroll
  for (int r = 0; r < 4; ++r){
    float s = 0.f, qq = 0.f;
    #pragma unroll
    for (int nf = 0; nf < 8; ++nf){ float v = acc[nf][r]; s += v; qq += v*v; }
    #pragma unroll
    for (int m = 1; m < 16; m <<= 1){ s += __shfl_xor(s, m); qq += __shfl_xor(qq, m); }
    float mu = s * 0.0078125f;
    float var = fmaxf(qq*0.0078125f - mu*mu, 0.f);
    float rstd = rsqrtf(var + 1e-5f);
    const int rC = rCb + r;
    #pragma unroll
    for (int nf = 0; nf < 8; ++nf){
      float hn = (acc[nf][r] - mu)*rstd*gc[nf] + bc[nf];
      acc[nf][r] = hn;
      h_lnB[(size_t)rC*DD + nf*16 + l15] = f2bf(hn);
    }
  }

  __syncthreads();   // WT no longer needed; reuse LDS as hb[64 n][128 d]
  #pragma unroll
  for (int r = 0; r < 4; ++r)
    #pragma unroll
    for (int nf = 0; nf < 8; ++nf)
      lds[(w*16 + grp*4 + r)*128 + nf*16 + l15] = f2bf(acc[nf][r]);
  __syncthreads();

  // write 2 hTt tiles (32 n each): thread tid -> (h2 = tid>>7, d = tid&127),
  // 4 chunks g: dest ((bB*128+nt0+h2)*128 + d)*32 + g*8 (coalesced 64B/thread)
  {
    const int r0 = blockIdx.x*64;
    const int bB = r0 >> 12;
    const int nt0 = (r0 & 4095) >> 5;
    U16* dstt = hTt + ((size_t)(bB*128 + nt0)*128)*32;
    const int h2 = tid >> 7, d = tid & 127;
    #pragma unroll
    for (int g = 0; g < 4; ++g){
      bfrag8 v;
      #pragma unroll
      for (int e = 0; e < 8; ++e)
        v[e] = (short)lds[(h2*32 + g*8 + e)*128 + d];
      *reinterpret_cast<bfrag8*>(dstt + ((size_t)(h2*128 + d))*32 + g*8) = v;
    }
  }
}

// ---------------- kernel 2: S = (1-adj)@h direct-to-register GEMM ----------------
// R8 structure (passing) + adjacency fully preloaded (yq, constant-indexed via
// full unroll) -> loop has only the 8 B-frag loads; all sync compiler-visible.
__global__ __launch_bounds__(512, 2) void k2_main(
    const U32* __restrict__ adjb, const U16* __restrict__ hTt,
    const U16* __restrict__ h_lnB, float* __restrict__ out)
{
  __shared__ U16 part[65536];                // 128 KB: 8 regions x [64 r][128 c] bf16
  const int tid = threadIdx.x;
  const int lane = tid & 63, w = tid >> 6;   // w = K-eighth
  const int l15 = lane & 15, grp = lane >> 4;
  const int bid = blockIdx.x;
  const int xcd = bid & 7;
  const int b = xcd >> 1;                    // batch pinned to XCD pair
  const int iblk = (((bid >> 3) << 1) | (xcd & 1)) * 64;
  const float CMASK = 0.2f * -9.0e15f;       // leaky(MASK_VAL), exact

  // ---- preload ALL adjacency words; keep this lane's k-byte (grp) per word ----
  U32 yq[4][4];                              // [row-frag][word-quad], byte sq = word q*4+sq
  #pragma unroll
  for (int f = 0; f < 4; ++f){
    const int4* ap = reinterpret_cast<const int4*>(
        adjb + (size_t)(iblk + f*16 + l15)*128 + w*16);
    #pragma unroll
    for (int q = 0; q < 4; ++q){
      int4 v = ap[q];
      const U32 sh = grp*8;
      yq[f][q] = ((((U32)v.x >> sh) & 0xffu)      ) |
                 ((((U32)v.y >> sh) & 0xffu) <<  8) |
                 ((((U32)v.z >> sh) & 0xffu) << 16) |
                 ((((U32)v.w >> sh) & 0xffu) << 24);
    }
  }

  // B-fragment base: tile (b*128 + w*16 + s), lane offset l15*32 + grp*8 shorts;
  // nf stride 512 shorts; s stride 4096 shorts. Wave's 8 loads/step = 1KB contig.
  const U16* bp = hTt + ((size_t)(b*128 + w*16)*128)*32 + l15*32 + grp*8;

  f32x4v acc[4][8] = {};

#define LOADB(P0,P1,P2,P3,P4,P5,P6,P7, S) do { \
    const U16* _q = bp + (size_t)(S)*4096; \
    P0 = *reinterpret_cast<const bfrag8*>(_q);        \
    P1 = *reinterpret_cast<const bfrag8*>(_q + 512);  \
    P2 = *reinterpret_cast<const bfrag8*>(_q + 1024); \
    P3 = *reinterpret_cast<const bfrag8*>(_q + 1536); \
    P4 = *reinterpret_cast<const bfrag8*>(_q + 2048); \
    P5 = *reinterpret_cast<const bfrag8*>(_q + 2560); \
    P6 = *reinterpret_cast<const bfrag8*>(_q + 3072); \
    P7 = *reinterpret_cast<const bfrag8*>(_q + 3584); } while(0)

#define COLM(CF, NF) do { \
    acc[0][NF] = __builtin_amdgcn_mfma_f32_16x16x32_bf16(a0, CF, acc[0][NF], 0,0,0); \
    acc[1][NF] = __builtin_amdgcn_mfma_f32_16x16x32_bf16(a1, CF, acc[1][NF], 0,0,0); \
    acc[2][NF] = __builtin_amdgcn_mfma_f32_16x16x32_bf16(a2, CF, acc[2][NF], 0,0,0); \
    acc[3][NF] = __builtin_amdgcn_mfma_f32_16x16x32_bf16(a3, CF, acc[3][NF], 0,0,0); } while(0)

#define COMPUTE(P0,P1,P2,P3,P4,P5,P6,P7, Y0,Y1,Y2,Y3) do { \
    bfrag8 a0 = afragb(Y0), a1 = afragb(Y1); \
    bfrag8 a2 = afragb(Y2), a3 = afragb(Y3); \
    COLM(P0, 0); COLM(P1, 1); COLM(P2, 2); COLM(P3, 3); \
    COLM(P4, 4); COLM(P5, 5); COLM(P6, 6); COLM(P7, 7); } while(0)

  bfrag8 A0,A1,A2,A3,A4,A5,A6,A7, B0,B1,B2,B3,B4,B5,B6,B7;

  LOADB(A0,A1,A2,A3,A4,A5,A6,A7, 0);

  #pragma unroll
  for (int it = 0; it < 8; ++it){
    const int s = it*2;                       // compile-time (full unroll)
    LOADB(B0,B1,B2,B3,B4,B5,B6,B7, s+1);
    COMPUTE(A0,A1,A2,A3,A4,A5,A6,A7,
            yq[0][s>>2] >> ((s&3)*8), yq[1][s>>2] >> ((s&3)*8),
            yq[2][s>>2] >> ((s&3)*8), yq[3][s>>2] >> ((s&3)*8));
    LOADB(A0,A1,A2,A3,A4,A5,A6,A7, s+2);      // s+2==16 on last iter: reads pad
    COMPUTE(B0,B1,B2,B3,B4,B5,B6,B7,
            yq[0][(s+1)>>2] >> (((s+1)&3)*8), yq[1][(s+1)>>2] >> (((s+1)&3)*8),
            yq[2][(s+1)>>2] >> (((s+1)&3)*8), yq[3][(s+1)>>2] >> (((s+1)&3)*8));
  }

  // ---- K-combine: bf16 partials in LDS, XOR-swizzled (2 lanes/bank = free) ----
  U16* reg = part + w*8192;
  #pragma unroll
  for (int f = 0; f < 4; ++f)
    #pragma unroll
    for (int nf = 0; nf < 8; ++nf){
      const int col = nf*16 + l15;
      #pragma unroll
      for (int r = 0; r < 4; ++r){
        const int lr = f*16 + grp*4 + r;
        reg[lr*128 + (col ^ (((lr>>2)&3)<<4))] = f2bf(acc[f][nf][r]);
      }
    }
  __syncthreads();

  #pragma unroll
  for (int rr = 0; rr < 8; ++rr){
    const int row = w*8 + rr;
    const int ci = row*64 + (lane ^ (((row>>2)&3)<<3));   // u32 index (row-const XOR)
    float s0 = 0.f, s1 = 0.f;
    #pragma unroll
    for (int q = 0; q < 8; ++q){
      U32 p = reinterpret_cast<const U32*>(part)[q*4096 + ci];
      s0 += bf2f(p & 0xffffu); s1 += bf2f(p >> 16);
    }
    const float h0 = CMASK * s0, h1 = CMASK * s1;
    const float e0 = h0 > 0.f ? h0 : __expf(h0) - 1.f;
    const float e1 = h1 > 0.f ? h1 : __expf(h1) - 1.f;
    const size_t o = ((size_t)b*NN + iblk + row)*DD + 2*lane;
    const U32 hl = *reinterpret_cast<const U32*>(h_lnB + o);
    float2 ov; ov.x = e0 + bf2f(hl & 0xffffu); ov.y = e1 + bf2f(hl >> 16);
    *reinterpret_cast<float2*>(out + o) = ov;
  }
#undef COLM
#undef COMPUTE
#undef LOADB
}

extern "C" void kernel_launch(void* const* d_in, const int* in_sizes, int n_in,
                              void* d_out, int out_size, void* d_ws, size_t ws_size,
                              hipStream_t stream) {
  const float* x     = (const float*)d_in[0];
  const int*   adj   = (const int*)  d_in[1];
  const float* W     = (const float*)d_in[2];
  const float* nw    = (const float*)d_in[5];
  const float* nb    = (const float*)d_in[6];
  const float* gamma = (const float*)d_in[7];
  const float* beta  = (const float*)d_in[8];
  float* out = (float*)d_out;

  char* ws = (char*)d_ws;
  U16*   h_lnB = (U16*)(ws);                            // 4 MB
  U16*   hTt   = (U16*)(ws + 4*1024*1024);              // 4 MB + 16 KB pad
  U16*   WT    = (U16*)(ws + 8*1024*1024 + 16*1024);    // 32 KB
  U32*   adjb  = (U32*)(ws + 9*1024*1024);              // 2 MB

  k0_combo<<<dim3(2112), dim3(256), 0, stream>>>(adj, adjb, W, WT);
  k1_prep <<<dim3(256),  dim3(256), 0, stream>>>(x, WT, nw, nb, gamma, beta,
                                                 h_lnB, hTt);
  k2_main <<<dim3(256),  dim3(512), 0, stream>>>(adjb, hTt, h_lnB, out);
}

// Round 12
// 56.467 us; speedup vs baseline: 1.0205x; 1.0205x over previous
//
#include <hip/hip_runtime.h>
#include <hip/hip_bf16.h>

typedef short bfrag8 __attribute__((ext_vector_type(8)));
typedef float f32x4v __attribute__((ext_vector_type(4)));
typedef unsigned short U16;
typedef unsigned int U32;

#define NN 4096
#define DD 128

static __device__ __forceinline__ U16 f2bf(float f){
  union { __hip_bfloat16 b; U16 u; } cv;
  cv.b = __float2bfloat16(f);
  return cv.u;
}

static __device__ __forceinline__ float bf2f(U32 u){
  union { float f; U32 u; } cv;
  cv.u = u << 16;
  return cv.f;
}

// A-fragment from inverted adjacency bits (low byte): bit=0 -> 1.0bf16, bit=1 -> 0
static __device__ __forceinline__ bfrag8 afragb(U32 y){
  bfrag8 a;
  #pragma unroll
  for (int e = 0; e < 8; ++e) a[e] = (y & (1u<<e)) ? (short)0 : (short)0x3F80;
  return a;
}

// ---------------- kernel 0: adj pack TRANSPOSED (blocks 0..2047) + W^T (2048..2111) --
// adjbT[g*4096 + row] bit j = adj[row][g*32 + j] != 0  (g = 32-col group).
__global__ __launch_bounds__(256) void k0_combo(const int* __restrict__ adj,
                                                U32* __restrict__ adjbT,
                                                const float* __restrict__ W,
                                                U16* __restrict__ WT){
  if (blockIdx.x >= 2048){
    int i = (blockIdx.x - 2048)*256 + threadIdx.x;  // i = d*128 + dp
    int d = i >> 7, dp = i & 127;
    WT[dp*128 + d] = f2bf(W[i]);
    return;
  }
  const int g   = blockIdx.x >> 4;                  // 0..127
  const int row = (blockIdx.x & 15)*256 + threadIdx.x;
  const int4* src = reinterpret_cast<const int4*>(adj + (size_t)row*NN + g*32);
  int4 v[8];
  #pragma unroll
  for (int c = 0; c < 8; ++c) v[c] = src[c];
  U32 m = 0;
  #pragma unroll
  for (int c = 0; c < 8; ++c){
    m |= (v[c].x != 0 ? 1u : 0u) << (c*4);
    m |= (v[c].y != 0 ? 2u : 0u) << (c*4);
    m |= (v[c].z != 0 ? 4u : 0u) << (c*4);
    m |= (v[c].w != 0 ? 8u : 0u) << (c*4);
  }
  adjbT[(size_t)g*4096 + row] = m;
}

// ---------------- kernel 1: x2 = x*(nw+1)+nb; h = LN(x2@W) via MFMA;
// writes h_lnB (bf16 row-major) and hTt: element (b,n,d) at
// ((b*128 + n/32)*128 + d)*32 + (n&31) shorts.
__global__ __launch_bounds__(256) void k1_prep(
    const float* __restrict__ x, const U16* __restrict__ WT,
    const float* __restrict__ nw, const float* __restrict__ nb,
    const float* __restrict__ gamma, const float* __restrict__ beta,
    U16* __restrict__ h_lnB, U16* __restrict__ hTt)
{
  __shared__ U16 lds[16384];                 // 32 KB: WT (swizzled), later hb[64][128]
  const int tid = threadIdx.x;
  const int lane = tid & 63, w = tid >> 6;
  const int l15 = lane & 15, grp = lane >> 4;

  #pragma unroll
  for (int q = 0; q < 8; ++q){
    int cid = q*256 + tid;
    int dp = cid >> 4, c = cid & 15;
    *reinterpret_cast<int4*>(lds + dp*128 + ((c*8) ^ ((dp&15)<<3))) =
        *reinterpret_cast<const int4*>(WT + cid*8);
  }
  __syncthreads();

  const int rA = blockIdx.x*64 + w*16 + l15;
  const int nA = rA & 4095;
  const float wgt = nw[nA] + 1.0f, bia = nb[nA];
  const float* xr = x + (size_t)rA*DD;

  f32x4v acc[8] = {};
  #pragma unroll
  for (int ks = 0; ks < 4; ++ks){
    int d8 = ks*32 + grp*8;
    float4 xa = *reinterpret_cast<const float4*>(xr + d8);
    float4 xb = *reinterpret_cast<const float4*>(xr + d8 + 4);
    bfrag8 af;
    af[0] = (short)f2bf(xa.x*wgt + bia);
    af[1] = (short)f2bf(xa.y*wgt + bia);
    af[2] = (short)f2bf(xa.z*wgt + bia);
    af[3] = (short)f2bf(xa.w*wgt + bia);
    af[4] = (short)f2bf(xb.x*wgt + bia);
    af[5] = (short)f2bf(xb.y*wgt + bia);
    af[6] = (short)f2bf(xb.z*wgt + bia);
    af[7] = (short)f2bf(xb.w*wgt + bia);
    #pragma unroll
    for (int nf = 0; nf < 8; ++nf){
      int dp = nf*16 + l15;
      bfrag8 bf = *reinterpret_cast<const bfrag8*>(
          lds + dp*128 + ((((ks*4 + grp)*8)) ^ ((dp&15)<<3)));
      acc[nf] = __builtin_amdgcn_mfma_f32_16x16x32_bf16(af, bf, acc[nf], 0, 0, 0);
    }
  }

  float gc[8], bc[8];
  #pragma unroll
  for (int nf = 0; nf < 8; ++nf){
    int col = nf*16 + l15;
    gc[nf] = gamma[col]; bc[nf] = beta[col];
  }

  // C/D layout: col = lane&15, row = (lane>>4)*4 + r (m89-verified)
  const int rCb = blockIdx.x*64 + w*16 + grp*4;
  #pragma unroll
  for (int r = 0; r < 4; ++r){
    float s = 0.f, qq = 0.f;
    #pragma unroll
    for (int nf = 0; nf < 8; ++nf){ float v = acc[nf][r]; s += v; qq += v*v; }
    #pragma unroll
    for (int m = 1; m < 16; m <<= 1){ s += __shfl_xor(s, m); qq += __shfl_xor(qq, m); }
    float mu = s * 0.0078125f;
    float var = fmaxf(qq*0.0078125f - mu*mu, 0.f);
    float rstd = rsqrtf(var + 1e-5f);
    const int rC = rCb + r;
    #pragma unroll
    for (int nf = 0; nf < 8; ++nf){
      float hn = (acc[nf][r] - mu)*rstd*gc[nf] + bc[nf];
      acc[nf][r] = hn;
      h_lnB[(size_t)rC*DD + nf*16 + l15] = f2bf(hn);
    }
  }

  __syncthreads();   // WT no longer needed; reuse LDS as hb[64 n][128 d]
  #pragma unroll
  for (int r = 0; r < 4; ++r)
    #pragma unroll
    for (int nf = 0; nf < 8; ++nf)
      lds[(w*16 + grp*4 + r)*128 + nf*16 + l15] = f2bf(acc[nf][r]);
  __syncthreads();

  {
    const int r0 = blockIdx.x*64;
    const int bB = r0 >> 12;
    const int nt0 = (r0 & 4095) >> 5;
    U16* dstt = hTt + ((size_t)(bB*128 + nt0)*128)*32;
    const int h2 = tid >> 7, d = tid & 127;
    #pragma unroll
    for (int g = 0; g < 4; ++g){
      bfrag8 v;
      #pragma unroll
      for (int e = 0; e < 8; ++e)
        v[e] = (short)lds[(h2*32 + g*8 + e)*128 + d];
      *reinterpret_cast<bfrag8*>(dstt + ((size_t)(h2*128 + d))*32 + g*8) = v;
    }
  }
}

// ---------------- kernel 2: S = (1-adj)@h direct-to-register GEMM ----------------
// 51.7µs structure + 2-steps-ahead 3-banked prefetch (F[3][8], wv[3][4]; all
// indices compile-time via full unroll). All load->use sync compiler-visible.
__global__ __launch_bounds__(512, 2) void k2_main(
    const U32* __restrict__ adjbT, const U16* __restrict__ hTt,
    const U16* __restrict__ h_lnB, float* __restrict__ out)
{
  __shared__ U16 part[65536];                // 128 KB: 8 regions x [64 r][128 c] bf16
  const int tid = threadIdx.x;
  const int lane = tid & 63, w = tid >> 6;   // w = K-eighth
  const int l15 = lane & 15, grp = lane >> 4;
  const int bid = blockIdx.x;
  const int xcd = bid & 7;
  const int b = xcd >> 1;                    // batch pinned to XCD pair
  const int iblk = (((bid >> 3) << 1) | (xcd & 1)) * 64;
  const float CMASK = 0.2f * -9.0e15f;       // leaky(MASK_VAL), exact

  // transposed adj bits: word (g = w*16+s) for rows iblk+f*16+l15 -> consecutive u32
  const U32* ar = adjbT + (size_t)(w*16)*4096 + iblk + l15;

  // B-fragment base: tile (b*128 + w*16 + s), lane offset l15*32 + grp*8 shorts;
  // nf stride 512 shorts; s stride 4096 shorts. Wave's 8 loads/step = 1KB contig.
  const U16* bp = hTt + ((size_t)(b*128 + w*16)*128)*32 + l15*32 + grp*8;

  f32x4v acc[4][8] = {};
  bfrag8 F[3][8];                            // 3 banks (2-steps-ahead prefetch)
  U32 wv[3][4];

#define LOADF(BK, S) do { \
    const U16* _q = bp + (size_t)(S)*4096; \
    F[BK][0] = *reinterpret_cast<const bfrag8*>(_q);        \
    F[BK][1] = *reinterpret_cast<const bfrag8*>(_q + 512);  \
    F[BK][2] = *reinterpret_cast<const bfrag8*>(_q + 1024); \
    F[BK][3] = *reinterpret_cast<const bfrag8*>(_q + 1536); \
    F[BK][4] = *reinterpret_cast<const bfrag8*>(_q + 2048); \
    F[BK][5] = *reinterpret_cast<const bfrag8*>(_q + 2560); \
    F[BK][6] = *reinterpret_cast<const bfrag8*>(_q + 3072); \
    F[BK][7] = *reinterpret_cast<const bfrag8*>(_q + 3584); } while(0)

#define LOADW(BK, S) do { \
    wv[BK][0] = ar[(size_t)(S)*4096];      \
    wv[BK][1] = ar[(size_t)(S)*4096 + 16]; \
    wv[BK][2] = ar[(size_t)(S)*4096 + 32]; \
    wv[BK][3] = ar[(size_t)(S)*4096 + 48]; } while(0)

#define COLM(CF, NF) do { \
    acc[0][NF] = __builtin_amdgcn_mfma_f32_16x16x32_bf16(a0, CF, acc[0][NF], 0,0,0); \
    acc[1][NF] = __builtin_amdgcn_mfma_f32_16x16x32_bf16(a1, CF, acc[1][NF], 0,0,0); \
    acc[2][NF] = __builtin_amdgcn_mfma_f32_16x16x32_bf16(a2, CF, acc[2][NF], 0,0,0); \
    acc[3][NF] = __builtin_amdgcn_mfma_f32_16x16x32_bf16(a3, CF, acc[3][NF], 0,0,0); } while(0)

  LOADF(0, 0); LOADW(0, 0);
  LOADF(1, 1); LOADW(1, 1);

  #pragma unroll
  for (int s = 0; s < 16; ++s){              // full unroll: s, s%3 compile-time
    if (s + 2 < 16){ LOADF((s+2)%3, s+2); LOADW((s+2)%3, s+2); }
    const int bk = s % 3;
    bfrag8 a0 = afragb(wv[bk][0] >> (grp*8));
    bfrag8 a1 = afragb(wv[bk][1] >> (grp*8));
    bfrag8 a2 = afragb(wv[bk][2] >> (grp*8));
    bfrag8 a3 = afragb(wv[bk][3] >> (grp*8));
    COLM(F[bk][0], 0); COLM(F[bk][1], 1); COLM(F[bk][2], 2); COLM(F[bk][3], 3);
    COLM(F[bk][4], 4); COLM(F[bk][5], 5); COLM(F[bk][6], 6); COLM(F[bk][7], 7);
  }

  // ---- K-combine: bf16 partials in LDS, XOR-swizzled (2 lanes/bank = free) ----
  U16* reg = part + w*8192;
  #pragma unroll
  for (int f = 0; f < 4; ++f)
    #pragma unroll
    for (int nf = 0; nf < 8; ++nf){
      const int col = nf*16 + l15;
      #pragma unroll
      for (int r = 0; r < 4; ++r){
        const int lr = f*16 + grp*4 + r;
        reg[lr*128 + (col ^ (((lr>>2)&3)<<4))] = f2bf(acc[f][nf][r]);
      }
    }
  __syncthreads();

  #pragma unroll
  for (int rr = 0; rr < 8; ++rr){
    const int row = w*8 + rr;
    const int ci = row*64 + (lane ^ (((row>>2)&3)<<3));   // u32 index (row-const XOR)
    float s0 = 0.f, s1 = 0.f;
    #pragma unroll
    for (int q = 0; q < 8; ++q){
      U32 p = reinterpret_cast<const U32*>(part)[q*4096 + ci];
      s0 += bf2f(p & 0xffffu); s1 += bf2f(p >> 16);
    }
    const float h0 = CMASK * s0, h1 = CMASK * s1;
    const float e0 = h0 > 0.f ? h0 : __expf(h0) - 1.f;
    const float e1 = h1 > 0.f ? h1 : __expf(h1) - 1.f;
    const size_t o = ((size_t)b*NN + iblk + row)*DD + 2*lane;
    const U32 hl = *reinterpret_cast<const U32*>(h_lnB + o);
    float2 ov; ov.x = e0 + bf2f(hl & 0xffffu); ov.y = e1 + bf2f(hl >> 16);
    *reinterpret_cast<float2*>(out + o) = ov;
  }
#undef COLM
#undef LOADW
#undef LOADF
}

extern "C" void kernel_launch(void* const* d_in, const int* in_sizes, int n_in,
                              void* d_out, int out_size, void* d_ws, size_t ws_size,
                              hipStream_t stream) {
  const float* x     = (const float*)d_in[0];
  const int*   adj   = (const int*)  d_in[1];
  const float* W     = (const float*)d_in[2];
  const float* nw    = (const float*)d_in[5];
  const float* nb    = (const float*)d_in[6];
  const float* gamma = (const float*)d_in[7];
  const float* beta  = (const float*)d_in[8];
  float* out = (float*)d_out;

  char* ws = (char*)d_ws;
  U16*   h_lnB = (U16*)(ws);                            // 4 MB
  U16*   hTt   = (U16*)(ws + 4*1024*1024);              // 4 MB + 16 KB pad
  U16*   WT    = (U16*)(ws + 8*1024*1024 + 16*1024);    // 32 KB
  U32*   adjbT = (U32*)(ws + 9*1024*1024);              // 2 MB

  k0_combo<<<dim3(2112), dim3(256), 0, stream>>>(adj, adjbT, W, WT);
  k1_prep <<<dim3(256),  dim3(256), 0, stream>>>(x, WT, nw, nb, gamma, beta,
                                                 h_lnB, hTt);
  k2_main <<<dim3(256),  dim3(512), 0, stream>>>(adjbT, hTt, h_lnB, out);
}